// Round 8
// baseline (592.077 us; speedup 1.0000x reference)
//
#include <hip/hip_runtime.h>
#include <math.h>

#define HDIM 2048
#define NK 4
#define NIT 9
#define NSID 11            // 0=x, 1=h, 2=zero, 3..10 = G0..G7
#define MAXPAIRS 36
#define MAXBASES (MAXPAIRS*8)   // 288
#define NCH 64                  // h-chunks per matrix
#define CHROWS 32               // rows per chunk
#define NACC 16                 // G-accum blocks (float4)
#define NBS (MAXBASES + NACC)

// ---- workspace layout (in 4-byte slots) ----
#define CACHE_SZ (NSID*2*NK*HDIM)            // cache[sid][m(L/R)][k][d]
#define OFF_CACHE 0
#define OFF_AMAX   (OFF_CACHE + CACHE_SZ)    // 288 floats
#define OFF_DOTR_D (OFF_AMAX + MAXBASES)     // 288 doubles (576 slots)
#define OFF_DOTS_D (OFF_DOTR_D + 2*MAXBASES)
#define OFF_DOTT_D (OFF_DOTS_D + 2*MAXBASES)
#define PLAN_SZ 152
#define OFF_PLAN0 (OFF_DOTT_D + 2*MAXBASES)
#define OFF_PLAN1 (OFF_PLAN0 + PLAN_SZ)
#define OFF_STATE (OFF_PLAN1 + PLAN_SZ)      // ints: [0]=lc, [1..8]=comp_src
#define OFF_SUMW_D (OFF_STATE + 16)          // double (even slot)
#define OFF_GT8   (OFF_SUMW_D + 16)          // 8*HDIM partial G sums
#define OFF_PART  (OFF_GT8 + 8*HDIM)         // 16*NCH*HDIM vecmat partials (8 MB)

__device__ __forceinline__ float wredmax(float v){
#pragma unroll
  for(int o=32;o;o>>=1) v = fmaxf(v,__shfl_down(v,o,64));
  return v;
}
__device__ __forceinline__ float wredsum(float v){
#pragma unroll
  for(int o=32;o;o>>=1) v += __shfl_down(v,o,64);
  return v;
}
__device__ __forceinline__ double wredsumd(double v){
#pragma unroll
  for(int o=32;o;o>>=1) v += __shfl_down(v,o,64);
  return v;
}

// replicate _valid_pairs + sid resolution
__device__ void build_plan(int r, int lc, const int* cs, int* plan){
  int nc = 3 + lc;
  int nri = NIT - r;
  int np = 0;
  for(int i=0;i<nc-1;i++){
    for(int j=i+1;j<nc;j++){
      bool flag;
      if (nri == lc-1)      flag = (i>=3);
      else if (nri == lc)   flag = (j>=3);
      else                  flag = (nri > lc);
      if(flag){
        plan[8+np]            = i;
        plan[8+MAXPAIRS+np]   = j;
        plan[8+2*MAXPAIRS+np] = (i<3)? i : 3+cs[i-3];
        plan[8+3*MAXPAIRS+np] = (j<3)? j : 3+cs[j-3];
        np++;
      }
    }
  }
  plan[0]=nc; plan[1]=np; plan[2]=np*8;
}

// GEMV stage 1: block = (vec, combo, hc). 256 threads; thread t owns TWO
// independent float4 strips: cols 4t..4t+3 and 1024+4t..1024+4t+3.
// 32-row chunks, 64 chunks -> 512 blocks/vector (2 blocks/CU on r>0
// launches, 4/CU on the fused x+h launch) for ~2x in-flight bytes.
// Per-column order: fmaf h ascending within chunk; kreduce sums chunks
// in ascending order.
__global__ __launch_bounds__(256) void kvecmat(const float* __restrict__ va,
                                               const float* __restrict__ vb,
                                               const float* __restrict__ w,
                                               const float* __restrict__ L,
                                               const float* __restrict__ R,
                                               float* __restrict__ ws,
                                               int nvec){
  int bid = blockIdx.x;
  int tid = threadIdx.x;
  int nmain = nvec << 9;            // nvec*512 main blocks
  if (bid >= nmain){
    // ---- init role (32 extra blocks, only on the x+h launch) ----
    int ib = bid - nmain;
    for(int i = ib*256+tid; i < 8*HDIM; i += 32*256)
      ws[OFF_CACHE + 16*HDIM + i] = 0.f;          // zero candidate (sid 2)
    if (ib == 0){
      double s = 0.0;
      for(int d=tid; d<HDIM; d+=256) s += (double)w[d];
      s = wredsumd(s);
      __shared__ double red[4];
      int wv = tid>>6, ln = tid&63;
      if(!ln) red[wv]=s;
      __syncthreads();
      if(tid==0){
        *(double*)(ws + OFF_SUMW_D) = red[0]+red[1]+red[2]+red[3];
        int* st = (int*)(ws + OFF_STATE);
        for(int q=0;q<=8;q++) st[q]=0;
        build_plan(0, 0, st+1, (int*)(ws + OFF_PLAN0));
      }
    }
    return;
  }
  int vec   = bid >> 9;
  int b     = bid & 511;
  int combo = b >> 6;               // 0..7 : m(2) x k(4)
  int hc    = b & 63;               // 64 h-chunks of 32 rows
  const float* v = vec ? vb : va;
  __shared__ float vs[CHROWS];
  if (tid < CHROWS) vs[tid] = v[hc*CHROWS + tid];
  __syncthreads();
  int m = combo>>2, k = combo&3;
  const float* M = (m==0?L:R) + (size_t)k*HDIM*HDIM + (size_t)hc*CHROWS*HDIM + tid*4;
  float ax0=0.f, ay0=0.f, az0=0.f, aw0=0.f;
  float ax1=0.f, ay1=0.f, az1=0.f, aw1=0.f;
#pragma unroll 8
  for(int h=0; h<CHROWS; h++){
    const float4 f0 = *reinterpret_cast<const float4*>(M + (size_t)h*HDIM);
    const float4 f1 = *reinterpret_cast<const float4*>(M + (size_t)h*HDIM + 1024);
    float vv = vs[h];
    ax0 = fmaf(vv, f0.x, ax0); ay0 = fmaf(vv, f0.y, ay0);
    az0 = fmaf(vv, f0.z, az0); aw0 = fmaf(vv, f0.w, aw0);
    ax1 = fmaf(vv, f1.x, ax1); ay1 = fmaf(vv, f1.y, ay1);
    az1 = fmaf(vv, f1.z, az1); aw1 = fmaf(vv, f1.w, aw1);
  }
  float* P = ws + OFF_PART + ((size_t)(vec*8+combo)*NCH + hc)*HDIM + tid*4;
  float4 o0; o0.x=ax0; o0.y=ay0; o0.z=az0; o0.w=aw0;
  float4 o1; o1.x=ax1; o1.y=ay1; o1.z=az1; o1.w=aw1;
  *reinterpret_cast<float4*>(P) = o0;
  *reinterpret_cast<float4*>(P + 1024) = o1;
}

// GEMV stage 2: fixed-order (hc ascending) reduction of 64 chunk partials
// -> cache slot. float4; nvec*16 blocks.
__global__ __launch_bounds__(256) void kreduce(float* __restrict__ ws, int sid0){
  int b = blockIdx.x;
  int vec = b>>4, rem = b&15;
  int combo = rem>>1, dhalf = rem&1;
  int d = dhalf*1024 + threadIdx.x*4;
  const float* p = ws + OFF_PART + (size_t)(vec*8+combo)*NCH*HDIM + d;
  float sx=0.f, sy=0.f, sz=0.f, sw=0.f;
#pragma unroll
  for(int hc=0; hc<NCH; hc++){
    const float4 pf = *reinterpret_cast<const float4*>(p + (size_t)hc*HDIM);
    sx += pf.x; sy += pf.y; sz += pf.z; sw += pf.w;
  }
  int m = combo>>2, k = combo&3;
  int sid = sid0 + vec;
  float4 o; o.x=sx; o.y=sy; o.z=sz; o.w=sw;
  *reinterpret_cast<float4*>(ws + OFF_CACHE + ((size_t)(sid*2+m)*NK + k)*HDIM + d) = o;
}

// fused: blocks [0,MAXBASES) = per-base stats (float4 loads, double dots);
// blocks [MAXBASES, +NACC) = G partial accum (float4, element-math identical)
__global__ __launch_bounds__(256) void kbaseaccum(const float* __restrict__ bvec,
                                                  const float* __restrict__ w,
                                                  float* __restrict__ ws, int par){
  const int* plan = (const int*)(ws + (par ? OFF_PLAN1 : OFF_PLAN0));
  int nb = plan[2];
  int tid = threadIdx.x;
  if (blockIdx.x < MAXBASES){
    int t = blockIdx.x;
    if (t >= nb) return;
    int p = t>>3, k=(t>>1)&3, bf=t&1;
    int si = plan[8+2*MAXPAIRS+p], sj = plan[8+3*MAXPAIRS+p];
    const float* CL = ws + OFF_CACHE + ((size_t)(si*2+0)*NK + k)*HDIM;
    const float* CR = ws + OFF_CACHE + ((size_t)(sj*2+1)*NK + k)*HDIM;
    const float* bk = bvec + (size_t)k*HDIM;
    float am=0.f; double dr=0.0, ds=0.0, dt=0.0;
#pragma unroll
    for(int dd=0; dd<2; dd++){
      int d0 = dd*1024 + tid*4;
      const float4 a4 = *reinterpret_cast<const float4*>(CL + d0);
      const float4 c4 = *reinterpret_cast<const float4*>(CR + d0);
      const float4 b4 = *reinterpret_cast<const float4*>(bk + d0);
      const float4 w4 = *reinterpret_cast<const float4*>(w  + d0);
      float av[4] = {a4.x,a4.y,a4.z,a4.w};
      float cv[4] = {c4.x,c4.y,c4.z,c4.w};
      float bv[4] = {b4.x,b4.y,b4.z,b4.w};
      float wv4[4]= {w4.x,w4.y,w4.z,w4.w};
#pragma unroll
      for(int q=0;q<4;q++){
        float res = (bf==0) ? __fadd_rn(__fmul_rn(av[q],cv[q]), bv[q])
                            : __fadd_rn(__fadd_rn(av[q],cv[q]), bv[q]);
        float wd = wv4[q];
        am = fmaxf(am, fabsf(res));
        float sg = 1.0f/(1.0f+expf(-res));
        float th = tanhf(res);
        dr += (double)res*(double)wd;
        ds += (double)sg *(double)wd;
        dt += (double)th *(double)wd;
      }
    }
    am = wredmax(am); dr = wredsumd(dr); ds = wredsumd(ds); dt = wredsumd(dt);
    __shared__ double redd[4][3];
    __shared__ float  redm[4];
    int wv = tid>>6, ln = tid&63;
    if(!ln){ redm[wv]=am; redd[wv][0]=dr; redd[wv][1]=ds; redd[wv][2]=dt; }
    __syncthreads();
    if(!tid){
      float A=redm[0]; double Dr=redd[0][0], Ds=redd[0][1], Dt=redd[0][2];
      for(int q=1;q<4;q++){ A=fmaxf(A,redm[q]); Dr+=redd[q][0]; Ds+=redd[q][1]; Dt+=redd[q][2]; }
      ws[OFF_AMAX+t]=A;
      ((double*)(ws+OFF_DOTR_D))[t]=Dr;
      ((double*)(ws+OFF_DOTS_D))[t]=Ds;
      ((double*)(ws+OFF_DOTT_D))[t]=Dt;
    }
  } else {
    // G partial accum: 8 disjoint base-slices (t = bc, bc+8, ...) x 2 d-halves.
    // Per-element math and slice order identical to prior rounds.
    int bid2 = blockIdx.x - MAXBASES;
    int bc = bid2 >> 1;
    int db = bid2 & 1;
    int d = db*1024 + tid*4;
    float acc[4] = {0.f,0.f,0.f,0.f};
    for(int t=bc; t<nb; t+=8){
      int p=t>>3, k=(t>>1)&3, bf=t&1;
      int si = plan[8+2*MAXPAIRS+p], sj = plan[8+3*MAXPAIRS+p];
      const float4 a4 = *reinterpret_cast<const float4*>(ws + OFF_CACHE + ((size_t)(si*2+0)*NK+k)*HDIM + d);
      const float4 c4 = *reinterpret_cast<const float4*>(ws + OFF_CACHE + ((size_t)(sj*2+1)*NK+k)*HDIM + d);
      const float4 b4 = *reinterpret_cast<const float4*>(bvec + (size_t)k*HDIM + d);
      float av[4] = {a4.x,a4.y,a4.z,a4.w};
      float cv[4] = {c4.x,c4.y,c4.z,c4.w};
      float bv[4] = {b4.x,b4.y,b4.z,b4.w};
#pragma unroll
      for(int q=0;q<4;q++){
        float res = (bf==0) ? (av[q]*cv[q] + bv[q]) : (av[q] + cv[q] + bv[q]);
        float ex  = __expf(-res);
        float sig = 1.0f/(1.0f+ex);
        float ex2 = ex*ex;
        float th  = (1.0f-ex2)/(1.0f+ex2);
        acc[q] += sig + th;
      }
    }
    float4 o; o.x=acc[0]; o.y=acc[1]; o.z=acc[2]; o.w=acc[3];
    *reinterpret_cast<float4*>(ws + OFF_GT8 + (size_t)bc*HDIM + d) = o;
  }
}

// selection (double-precision scores) + fused G finalize + output dots
__global__ __launch_bounds__(256) void kselfin(const float* __restrict__ w,
                                               float* __restrict__ ws,
                                               float* __restrict__ out, int r){
  __shared__ double s4[MAXBASES][4];
  __shared__ int    sna[MAXBASES];
  __shared__ double tval[256];
  __shared__ int    tidx[256];
  __shared__ double tz[256];
  __shared__ int    tcnt[256];
  __shared__ double sh_smax;
  __shared__ float  sh_psel;
  __shared__ int    sh_c4;
  int par = r & 1;
  int* plan = (int*)(ws + (par ? OFF_PLAN1 : OFF_PLAN0));
  int nc = plan[0];
  int nb = plan[2];
  double sumw = *(const double*)(ws + OFF_SUMW_D);
  const double* DR = (const double*)(ws+OFF_DOTR_D);
  const double* DS = (const double*)(ws+OFF_DOTS_D);
  const double* DT = (const double*)(ws+OFF_DOTT_D);
  int tid = threadIdx.x;
  for(int t=tid; t<nb; t+=256){
    float A  = ws[OFF_AMAX+t];
    double Dr = DR[t], Ds = DS[t], Dt = DT[t];
    sna[t] = (A < 1.0f) ? 4 : 2;
    s4[t][0] = 0.001*Ds;         // sigmoid
    s4[t][1] = 0.001*Dt;         // tanh
    s4[t][2] = sumw - Dr;        // minus (valid only if na==4)
    s4[t][3] = Dr;               // identity
  }
  __syncthreads();
  // argmax with first-occurrence tie-break (flat q order == entry order)
  double best = -1e300; int bidx = 1<<30;
  for(int q=tid; q<nb*4; q+=256){
    int t=q>>2, a=q&3;
    if (a < sna[t]){
      double v = s4[t][a];
      if (v > best || (v==best && q < bidx)){ best=v; bidx=q; }
    }
  }
  tval[tid]=best; tidx[tid]=bidx;
  __syncthreads();
  if (tid==0){
    double bb=tval[0]; int bi=tidx[0];
    for(int u=1;u<256;u++)
      if (tval[u] > bb || (tval[u]==bb && tidx[u] < bi)){ bb=tval[u]; bi=tidx[u]; }
    sh_smax = bb;
    tidx[0] = bi;
  }
  __syncthreads();
  double smax = sh_smax;
  double s1 = s4[0][1];          // flat entry index 1 is always (base0, tanh)
  double z = 0.0; int cnt = 0;
  for(int q=tid; q<nb*4; q+=256){
    int t=q>>2, a=q&3;
    if (a < sna[t]){
      double v = s4[t][a];
      z += exp(v - smax);
      cnt += (v < s1) ? 1 : 0;
    }
  }
  tz[tid]=z; tcnt[tid]=cnt;
  __syncthreads();
  if (tid==0){
    int bi = tidx[0];
    double Z=0.0; int rank=0;
    for(int u=0;u<256;u++){ Z += tz[u]; rank += tcnt[u]; }
    // score of entry nc-2 (softmax prob numerator)
    int need = nc-2, e=0; double s_sel=0.0;
    for(int t=0;t<nb;t++){
      int n = sna[t];
      if (need < e+n){ s_sel = s4[t][need-e]; break; }
      e += n;
    }
    double psel = exp(s_sel - smax) / Z;
    // second_idx = rank of s[1] used as FLAT index into entries (original bug);
    // output3[r] == scores[second_idx], emit directly.
    int e2=0; double ssec=0.0;
    for(int t=0;t<nb;t++){
      int n = sna[t];
      if (rank < e2+n){ ssec = s4[t][rank-e2]; break; }
      e2 += n;
    }
    out[10*HDIM + 9 + r] = (float)ssec;
    int c4=0;
    for(int t=0;t<nb;t++) c4 += (sna[t]==4) ? 1 : 0;
    int mt = bi>>2;
    int mp = mt>>3;
    int ci = plan[8+mp], cj = plan[8+MAXPAIRS+mp];
    sh_psel = (float)psel;
    sh_c4   = c4;
    // comp_src update (replicates reference branch rules exactly)
    int* st = (int*)(ws + OFF_STATE);
    int lc = st[0];
    int* cs = st+1;
    if (ci>2 && cj>2){
      cs[ci-3] = r;
      for(int q2=cj-3; q2<lc-1; q2++) cs[q2]=cs[q2+1];
      lc--;
    } else if (ci<=2 && cj>2){
      cs[cj-3] = r;
    } else {
      cs[lc] = r; lc++;
    }
    st[0]=lc;
    if (r+1 < NIT)
      build_plan(r+1, lc, cs, (int*)(ws + ((par^1) ? OFF_PLAN1 : OFF_PLAN0)));
  }
  __syncthreads();
  // ---- fused finalize: G[r] from 8 fixed-order slices, G@w dot, output writes ----
  float psel = sh_psel;
  float c4f  = (float)sh_c4;
  float dot = 0.f;
#pragma unroll
  for(int q=0;q<8;q++){
    int d = q*256 + tid;
    float s = 0.f;
#pragma unroll
    for(int bc=0; bc<8; bc++) s += ws[OFF_GT8 + (size_t)bc*HDIM + d];
    float g = psel * (0.001f*s + c4f);
    out[HDIM + (size_t)r*HDIM + d] = g;
    if (r == NIT-1) out[d] = g;
    dot = fmaf(g, w[d], dot);
  }
  dot = wredsum(dot);
  __shared__ float redf[4];
  int wv = tid>>6, ln = tid&63;
  if(!ln) redf[wv]=dot;
  __syncthreads();
  if(!tid) out[10*HDIM + r] = redf[0]+redf[1]+redf[2]+redf[3];
}

extern "C" void kernel_launch(void* const* d_in, const int* in_sizes, int n_in,
                              void* d_out, int out_size, void* d_ws, size_t ws_size,
                              hipStream_t stream){
  const float* x = (const float*)d_in[0];
  const float* h = (const float*)d_in[1];
  const float* L = (const float*)d_in[2];
  const float* R = (const float*)d_in[3];
  const float* b = (const float*)d_in[4];
  const float* w = (const float*)d_in[5];
  float* out = (float*)d_out;
  float* ws  = (float*)d_ws;

  kvecmat<<<1024+32,256,0,stream>>>(x, h, w, L, R, ws, 2);  // x,h GEMVs + init
  kreduce<<<32,256,0,stream>>>(ws, 0);                      // sids 0,1
  for(int r=0;r<NIT;r++){
    if (r > 0){
      kvecmat<<<512,256,0,stream>>>(out + HDIM + (size_t)(r-1)*HDIM, nullptr, w, L, R, ws, 1);
      kreduce<<<16,256,0,stream>>>(ws, 3+(r-1));
    }
    kbaseaccum<<<NBS,256,0,stream>>>(b, w, ws, r&1);
    kselfin<<<1,256,0,stream>>>(w, ws, out, r);
  }
}

// Round 10
// 576.839 us; speedup vs baseline: 1.0264x; 1.0264x over previous
//
#include <hip/hip_runtime.h>
#include <math.h>

#define HDIM 2048
#define NK 4
#define NIT 9
#define NSID 11            // 0=x, 1=h, 2=zero, 3..10 = G0..G7
#define MAXPAIRS 36
#define MAXBASES (MAXPAIRS*8)   // 288

// ---- workspace layout (in 4-byte slots) ----
#define CACHE_SZ (NSID*2*NK*HDIM)            // cache[sid][m(L/R)][k][d]
#define OFF_CACHE 0
#define OFF_AMAX   (OFF_CACHE + CACHE_SZ)    // 288 floats
#define OFF_DOTR_D (OFF_AMAX + MAXBASES)     // 288 doubles (576 slots)
#define OFF_DOTS_D (OFF_DOTR_D + 2*MAXBASES)
#define OFF_DOTT_D (OFF_DOTS_D + 2*MAXBASES)
#define PLAN_SZ 152
#define OFF_PLAN0 (OFF_DOTT_D + 2*MAXBASES)
#define OFF_PLAN1 (OFF_PLAN0 + PLAN_SZ)
#define OFF_STATE (OFF_PLAN1 + PLAN_SZ)      // ints: [0]=lc, [1..8]=comp_src
#define OFF_SUMW_D (OFF_STATE + 16)          // double (even slot)
#define OFF_GT8   (OFF_SUMW_D + 16)          // 8*HDIM partial G sums
#define OFF_PART  (OFF_GT8 + 8*HDIM)         // 16*32*HDIM vecmat partials

typedef float vf4 __attribute__((ext_vector_type(4)));

__device__ __forceinline__ vf4 ntload4(const float* p){
  return __builtin_nontemporal_load(reinterpret_cast<const vf4*>(p));
}
__device__ __forceinline__ void ntstore4(float* p, vf4 v){
  __builtin_nontemporal_store(v, reinterpret_cast<vf4*>(p));
}

__device__ __forceinline__ float wredmax(float v){
#pragma unroll
  for(int o=32;o;o>>=1) v = fmaxf(v,__shfl_down(v,o,64));
  return v;
}
__device__ __forceinline__ float wredsum(float v){
#pragma unroll
  for(int o=32;o;o>>=1) v += __shfl_down(v,o,64);
  return v;
}
__device__ __forceinline__ double wredsumd(double v){
#pragma unroll
  for(int o=32;o;o>>=1) v += __shfl_down(v,o,64);
  return v;
}

// replicate _valid_pairs + sid resolution
__device__ void build_plan(int r, int lc, const int* cs, int* plan){
  int nc = 3 + lc;
  int nri = NIT - r;
  int np = 0;
  for(int i=0;i<nc-1;i++){
    for(int j=i+1;j<nc;j++){
      bool flag;
      if (nri == lc-1)      flag = (i>=3);
      else if (nri == lc)   flag = (j>=3);
      else                  flag = (nri > lc);
      if(flag){
        plan[8+np]            = i;
        plan[8+MAXPAIRS+np]   = j;
        plan[8+2*MAXPAIRS+np] = (i<3)? i : 3+cs[i-3];
        plan[8+3*MAXPAIRS+np] = (j<3)? j : 3+cs[j-3];
        np++;
      }
    }
  }
  plan[0]=nc; plan[1]=np; plan[2]=np*8;
}

// GEMV stage 1: block = (vec, combo, hc). 256 threads; 64-row chunks (32/vec).
// FOUR independent load streams per thread: {rows 0-31, rows 32-63} x
// {cols 4t..4t+3, 1024+4t..1024+4t+3}, separate accumulators, lo+hi combined
// at the end (association change of the class R8 validated). PART written
// NON-TEMPORAL so L+R stay L3-resident across the 9 sequential GEMVs.
__global__ __launch_bounds__(256) void kvecmat(const float* __restrict__ va,
                                               const float* __restrict__ vb,
                                               const float* __restrict__ w,
                                               const float* __restrict__ L,
                                               const float* __restrict__ R,
                                               float* __restrict__ ws,
                                               int nvec){
  int bid = blockIdx.x;
  int tid = threadIdx.x;
  int nmain = nvec << 8;            // nvec*256 main blocks
  if (bid >= nmain){
    // ---- init role (32 extra blocks, only on the x+h launch) ----
    int ib = bid - nmain;
    for(int i = ib*256+tid; i < 8*HDIM; i += 32*256)
      ws[OFF_CACHE + 16*HDIM + i] = 0.f;          // zero candidate (sid 2)
    if (ib == 0){
      double s = 0.0;
      for(int d=tid; d<HDIM; d+=256) s += (double)w[d];
      s = wredsumd(s);
      __shared__ double red[4];
      int wv = tid>>6, ln = tid&63;
      if(!ln) red[wv]=s;
      __syncthreads();
      if(tid==0){
        *(double*)(ws + OFF_SUMW_D) = red[0]+red[1]+red[2]+red[3];
        int* st = (int*)(ws + OFF_STATE);
        for(int q=0;q<=8;q++) st[q]=0;
        build_plan(0, 0, st+1, (int*)(ws + OFF_PLAN0));
      }
    }
    return;
  }
  int vec   = bid >> 8;
  int b     = bid & 255;
  int combo = b >> 5;               // 0..7 : m(2) x k(4)
  int hc    = b & 31;               // 32 h-chunks of 64 rows
  const float* v = vec ? vb : va;
  __shared__ float vs[64];
  if (tid < 64) vs[tid] = v[hc*64 + tid];
  __syncthreads();
  int m = combo>>2, k = combo&3;
  const float* M = (m==0?L:R) + (size_t)k*HDIM*HDIM + (size_t)hc*64*HDIM + tid*4;
  float ax0=0.f,ay0=0.f,az0=0.f,aw0=0.f, ax1=0.f,ay1=0.f,az1=0.f,aw1=0.f;
  float bx0=0.f,by0=0.f,bz0=0.f,bw0=0.f, bx1=0.f,by1=0.f,bz1=0.f,bw1=0.f;
#pragma unroll 8
  for(int h=0; h<32; h++){
    const float4 f0 = *reinterpret_cast<const float4*>(M + (size_t)h*HDIM);
    const float4 f1 = *reinterpret_cast<const float4*>(M + (size_t)h*HDIM + 1024);
    const float4 g0 = *reinterpret_cast<const float4*>(M + (size_t)(32+h)*HDIM);
    const float4 g1 = *reinterpret_cast<const float4*>(M + (size_t)(32+h)*HDIM + 1024);
    float v0 = vs[h], v1 = vs[32+h];
    ax0 = fmaf(v0, f0.x, ax0); ay0 = fmaf(v0, f0.y, ay0);
    az0 = fmaf(v0, f0.z, az0); aw0 = fmaf(v0, f0.w, aw0);
    ax1 = fmaf(v0, f1.x, ax1); ay1 = fmaf(v0, f1.y, ay1);
    az1 = fmaf(v0, f1.z, az1); aw1 = fmaf(v0, f1.w, aw1);
    bx0 = fmaf(v1, g0.x, bx0); by0 = fmaf(v1, g0.y, by0);
    bz0 = fmaf(v1, g0.z, bz0); bw0 = fmaf(v1, g0.w, bw0);
    bx1 = fmaf(v1, g1.x, bx1); by1 = fmaf(v1, g1.y, by1);
    bz1 = fmaf(v1, g1.z, bz1); bw1 = fmaf(v1, g1.w, bw1);
  }
  float* P = ws + OFF_PART + ((size_t)(vec*8+combo)*32 + hc)*HDIM + tid*4;
  vf4 o0; o0.x=ax0+bx0; o0.y=ay0+by0; o0.z=az0+bz0; o0.w=aw0+bw0;
  vf4 o1; o1.x=ax1+bx1; o1.y=ay1+by1; o1.z=az1+bz1; o1.w=aw1+bw1;
  ntstore4(P, o0);
  ntstore4(P + 1024, o1);
}

// GEMV stage 2: fixed-order (hc ascending) reduction of 32 chunk partials
// -> cache (deterministic). PART reads non-temporal; cache stores normal.
__global__ __launch_bounds__(256) void kreduce(float* __restrict__ ws, int sid0){
  int b = blockIdx.x;            // nvec*16 blocks
  int vec = b>>4, rem = b&15;
  int combo = rem>>1, dhalf = rem&1;
  int d = dhalf*1024 + threadIdx.x*4;
  const float* p = ws + OFF_PART + (size_t)(vec*8+combo)*32*HDIM + d;
  float sx=0.f, sy=0.f, sz=0.f, sw=0.f;
#pragma unroll
  for(int hc=0; hc<32; hc++){
    const vf4 pf = ntload4(p + (size_t)hc*HDIM);
    sx += pf.x; sy += pf.y; sz += pf.z; sw += pf.w;
  }
  int m = combo>>2, k = combo&3;
  int sid = sid0 + vec;
  float4 o; o.x=sx; o.y=sy; o.z=sz; o.w=sw;
  *reinterpret_cast<float4*>(ws + OFF_CACHE + ((size_t)(sid*2+m)*NK + k)*HDIM + d) = o;
}

// fused: blocks [0,MAXBASES) = per-base stats; blocks [MAXBASES, +64) = G partial accum
__global__ __launch_bounds__(256) void kbaseaccum(const float* __restrict__ bvec,
                                                  const float* __restrict__ w,
                                                  float* __restrict__ ws, int par){
  const int* plan = (const int*)(ws + (par ? OFF_PLAN1 : OFF_PLAN0));
  int nb = plan[2];
  if (blockIdx.x < MAXBASES){
    int t = blockIdx.x;
    if (t >= nb) return;
    int p = t>>3, k=(t>>1)&3, bf=t&1;
    int si = plan[8+2*MAXPAIRS+p], sj = plan[8+3*MAXPAIRS+p];
    const float* CL = ws + OFF_CACHE + ((size_t)(si*2+0)*NK + k)*HDIM;
    const float* CR = ws + OFF_CACHE + ((size_t)(sj*2+1)*NK + k)*HDIM;
    const float* bk = bvec + (size_t)k*HDIM;
    float am=0.f; double dr=0.0, ds=0.0, dt=0.0;
    for(int d=threadIdx.x; d<HDIM; d+=256){
      float a = CL[d], c = CR[d];
      float res = (bf==0) ? __fadd_rn(__fmul_rn(a,c), bk[d])
                          : __fadd_rn(__fadd_rn(a,c), bk[d]);
      float wd = w[d];
      am = fmaxf(am, fabsf(res));
      float sg = 1.0f/(1.0f+expf(-res));
      float th = tanhf(res);
      dr += (double)res*(double)wd;
      ds += (double)sg *(double)wd;
      dt += (double)th *(double)wd;
    }
    am = wredmax(am); dr = wredsumd(dr); ds = wredsumd(ds); dt = wredsumd(dt);
    __shared__ double redd[4][3];
    __shared__ float  redm[4];
    int wv = threadIdx.x>>6, ln = threadIdx.x&63;
    if(!ln){ redm[wv]=am; redd[wv][0]=dr; redd[wv][1]=ds; redd[wv][2]=dt; }
    __syncthreads();
    if(!threadIdx.x){
      float A=redm[0]; double Dr=redd[0][0], Ds=redd[0][1], Dt=redd[0][2];
      for(int q=1;q<4;q++){ A=fmaxf(A,redm[q]); Dr+=redd[q][0]; Ds+=redd[q][1]; Dt+=redd[q][2]; }
      ws[OFF_AMAX+t]=A;
      ((double*)(ws+OFF_DOTR_D))[t]=Dr;
      ((double*)(ws+OFF_DOTS_D))[t]=Ds;
      ((double*)(ws+OFF_DOTT_D))[t]=Dt;
    }
  } else {
    // G partial accum: 8 disjoint base-slices x 8 d-blocks (no atomics)
    int bid2 = blockIdx.x - MAXBASES;
    int bc = bid2 >> 3;
    int db = bid2 & 7;
    int d = db*256 + threadIdx.x;
    float acc = 0.f;
    for(int t=bc; t<nb; t+=8){
      int p=t>>3, k=(t>>1)&3, bf=t&1;
      int si = plan[8+2*MAXPAIRS+p], sj = plan[8+3*MAXPAIRS+p];
      float a = ws[OFF_CACHE + ((size_t)(si*2+0)*NK+k)*HDIM + d];
      float c = ws[OFF_CACHE + ((size_t)(sj*2+1)*NK+k)*HDIM + d];
      float res = (bf==0) ? (a*c + bvec[(size_t)k*HDIM+d]) : (a + c + bvec[(size_t)k*HDIM+d]);
      float ex  = __expf(-res);
      float sig = 1.0f/(1.0f+ex);
      float ex2 = ex*ex;
      float th  = (1.0f-ex2)/(1.0f+ex2);
      acc += sig + th;
    }
    __builtin_nontemporal_store(acc, &ws[OFF_GT8 + (size_t)bc*HDIM + d]);
  }
}

// selection (double-precision scores) + fused G finalize + output dots
__global__ __launch_bounds__(256) void kselfin(const float* __restrict__ w,
                                               float* __restrict__ ws,
                                               float* __restrict__ out, int r){
  __shared__ double s4[MAXBASES][4];
  __shared__ int    sna[MAXBASES];
  __shared__ double tval[256];
  __shared__ int    tidx[256];
  __shared__ double tz[256];
  __shared__ int    tcnt[256];
  __shared__ double sh_smax;
  __shared__ float  sh_psel;
  __shared__ int    sh_c4;
  int par = r & 1;
  int* plan = (int*)(ws + (par ? OFF_PLAN1 : OFF_PLAN0));
  int nc = plan[0];
  int nb = plan[2];
  double sumw = *(const double*)(ws + OFF_SUMW_D);
  const double* DR = (const double*)(ws+OFF_DOTR_D);
  const double* DS = (const double*)(ws+OFF_DOTS_D);
  const double* DT = (const double*)(ws+OFF_DOTT_D);
  int tid = threadIdx.x;
  for(int t=tid; t<nb; t+=256){
    float A  = ws[OFF_AMAX+t];
    double Dr = DR[t], Ds = DS[t], Dt = DT[t];
    sna[t] = (A < 1.0f) ? 4 : 2;
    s4[t][0] = 0.001*Ds;         // sigmoid
    s4[t][1] = 0.001*Dt;         // tanh
    s4[t][2] = sumw - Dr;        // minus (valid only if na==4)
    s4[t][3] = Dr;               // identity
  }
  __syncthreads();
  // argmax with first-occurrence tie-break (flat q order == entry order)
  double best = -1e300; int bidx = 1<<30;
  for(int q=tid; q<nb*4; q+=256){
    int t=q>>2, a=q&3;
    if (a < sna[t]){
      double v = s4[t][a];
      if (v > best || (v==best && q < bidx)){ best=v; bidx=q; }
    }
  }
  tval[tid]=best; tidx[tid]=bidx;
  __syncthreads();
  if (tid==0){
    double bb=tval[0]; int bi=tidx[0];
    for(int u=1;u<256;u++)
      if (tval[u] > bb || (tval[u]==bb && tidx[u] < bi)){ bb=tval[u]; bi=tidx[u]; }
    sh_smax = bb;
    tidx[0] = bi;
  }
  __syncthreads();
  double smax = sh_smax;
  double s1 = s4[0][1];          // flat entry index 1 is always (base0, tanh)
  double z = 0.0; int cnt = 0;
  for(int q=tid; q<nb*4; q+=256){
    int t=q>>2, a=q&3;
    if (a < sna[t]){
      double v = s4[t][a];
      z += exp(v - smax);
      cnt += (v < s1) ? 1 : 0;
    }
  }
  tz[tid]=z; tcnt[tid]=cnt;
  __syncthreads();
  if (tid==0){
    int bi = tidx[0];
    double Z=0.0; int rank=0;
    for(int u=0;u<256;u++){ Z += tz[u]; rank += tcnt[u]; }
    // score of entry nc-2 (softmax prob numerator)
    int need = nc-2, e=0; double s_sel=0.0;
    for(int t=0;t<nb;t++){
      int n = sna[t];
      if (need < e+n){ s_sel = s4[t][need-e]; break; }
      e += n;
    }
    double psel = exp(s_sel - smax) / Z;
    // second_idx = rank of s[1] used as FLAT index into entries (original bug);
    // output3[r] == scores[second_idx], emit directly.
    int e2=0; double ssec=0.0;
    for(int t=0;t<nb;t++){
      int n = sna[t];
      if (rank < e2+n){ ssec = s4[t][rank-e2]; break; }
      e2 += n;
    }
    out[10*HDIM + 9 + r] = (float)ssec;
    int c4=0;
    for(int t=0;t<nb;t++) c4 += (sna[t]==4) ? 1 : 0;
    int mt = bi>>2;
    int mp = mt>>3;
    int ci = plan[8+mp], cj = plan[8+MAXPAIRS+mp];
    sh_psel = (float)psel;
    sh_c4   = c4;
    // comp_src update (replicates reference branch rules exactly)
    int* st = (int*)(ws + OFF_STATE);
    int lc = st[0];
    int* cs = st+1;
    if (ci>2 && cj>2){
      cs[ci-3] = r;
      for(int q2=cj-3; q2<lc-1; q2++) cs[q2]=cs[q2+1];
      lc--;
    } else if (ci<=2 && cj>2){
      cs[cj-3] = r;
    } else {
      cs[lc] = r; lc++;
    }
    st[0]=lc;
    if (r+1 < NIT)
      build_plan(r+1, lc, cs, (int*)(ws + ((par^1) ? OFF_PLAN1 : OFF_PLAN0)));
  }
  __syncthreads();
  // ---- fused finalize: G[r] from 8 fixed-order slices, G@w dot, output writes ----
  float psel = sh_psel;
  float c4f  = (float)sh_c4;
  float dot = 0.f;
#pragma unroll
  for(int q=0;q<8;q++){
    int d = q*256 + tid;
    float s = 0.f;
#pragma unroll
    for(int bc=0; bc<8; bc++)
      s += __builtin_nontemporal_load(&ws[OFF_GT8 + (size_t)bc*HDIM + d]);
    float g = psel * (0.001f*s + c4f);
    out[HDIM + (size_t)r*HDIM + d] = g;
    if (r == NIT-1) out[d] = g;
    dot = fmaf(g, w[d], dot);
  }
  dot = wredsum(dot);
  __shared__ float redf[4];
  int wv = tid>>6, ln = tid&63;
  if(!ln) redf[wv]=dot;
  __syncthreads();
  if(!tid) out[10*HDIM + r] = redf[0]+redf[1]+redf[2]+redf[3];
}

extern "C" void kernel_launch(void* const* d_in, const int* in_sizes, int n_in,
                              void* d_out, int out_size, void* d_ws, size_t ws_size,
                              hipStream_t stream){
  const float* x = (const float*)d_in[0];
  const float* h = (const float*)d_in[1];
  const float* L = (const float*)d_in[2];
  const float* R = (const float*)d_in[3];
  const float* b = (const float*)d_in[4];
  const float* w = (const float*)d_in[5];
  float* out = (float*)d_out;
  float* ws  = (float*)d_ws;

  kvecmat<<<512+32,256,0,stream>>>(x, h, w, L, R, ws, 2);   // x,h GEMVs + init
  kreduce<<<32,256,0,stream>>>(ws, 0);                      // sids 0,1
  for(int r=0;r<NIT;r++){
    if (r > 0){
      kvecmat<<<256,256,0,stream>>>(out + HDIM + (size_t)(r-1)*HDIM, nullptr, w, L, R, ws, 1);
      kreduce<<<16,256,0,stream>>>(ws, 3+(r-1));
    }
    kbaseaccum<<<MAXBASES+64,256,0,stream>>>(b, w, ws, r&1);
    kselfin<<<1,256,0,stream>>>(w, ws, out, r);
  }
}

// Round 11
// 544.738 us; speedup vs baseline: 1.0869x; 1.0589x over previous
//
#include <hip/hip_runtime.h>
#include <math.h>

#define HDIM 2048
#define NK 4
#define NIT 9
#define NSID 11            // 0=x, 1=h, 2=zero, 3..10 = G0..G7
#define MAXPAIRS 36
#define MAXBASES (MAXPAIRS*8)   // 288
#define NACC 16
#define NBS (MAXBASES + NACC)

// ---- workspace layout (in 4-byte slots) ----
#define CACHE_SZ (NSID*2*NK*HDIM)            // cache[sid][m(L/R)][k][d]
#define OFF_CACHE 0
#define OFF_AMAX   (OFF_CACHE + CACHE_SZ)    // 288 floats
#define OFF_DOTR_D (OFF_AMAX + MAXBASES)     // 288 doubles (576 slots)
#define OFF_DOTS_D (OFF_DOTR_D + 2*MAXBASES)
#define OFF_DOTT_D (OFF_DOTS_D + 2*MAXBASES)
#define PLAN_SZ 152
#define OFF_PLAN0 (OFF_DOTT_D + 2*MAXBASES)
#define OFF_PLAN1 (OFF_PLAN0 + PLAN_SZ)
#define OFF_STATE (OFF_PLAN1 + PLAN_SZ)      // ints: [0]=lc, [1..8]=comp_src
#define OFF_SUMW_D (OFF_STATE + 16)          // double (even slot)
#define OFF_GT8   (OFF_SUMW_D + 16)          // 8*HDIM partial G sums
#define OFF_PART  (OFF_GT8 + 8*HDIM)         // 16*32*HDIM vecmat partials

__device__ __forceinline__ float wredmax(float v){
#pragma unroll
  for(int o=32;o;o>>=1) v = fmaxf(v,__shfl_down(v,o,64));
  return v;
}
__device__ __forceinline__ float wredsum(float v){
#pragma unroll
  for(int o=32;o;o>>=1) v += __shfl_down(v,o,64);
  return v;
}
__device__ __forceinline__ double wredsumd(double v){
#pragma unroll
  for(int o=32;o;o>>=1) v += __shfl_down(v,o,64);
  return v;
}

// replicate _valid_pairs + sid resolution
__device__ void build_plan(int r, int lc, const int* cs, int* plan){
  int nc = 3 + lc;
  int nri = NIT - r;
  int np = 0;
  for(int i=0;i<nc-1;i++){
    for(int j=i+1;j<nc;j++){
      bool flag;
      if (nri == lc-1)      flag = (i>=3);
      else if (nri == lc)   flag = (j>=3);
      else                  flag = (nri > lc);
      if(flag){
        plan[8+np]            = i;
        plan[8+MAXPAIRS+np]   = j;
        plan[8+2*MAXPAIRS+np] = (i<3)? i : 3+cs[i-3];
        plan[8+3*MAXPAIRS+np] = (j<3)? j : 3+cs[j-3];
        np++;
      }
    }
  }
  plan[0]=nc; plan[1]=np; plan[2]=np*8;
}

// GEMV stage 1 (exact R7 body): block = (vec, combo, hc). 256 threads; thread
// t owns TWO independent float4 strips: cols 4t..4t+3 and 1024+4t..1024+4t+3.
// Per-column fp order: fmaf h=0..63 ascending within chunk.
__global__ __launch_bounds__(256) void kvecmat(const float* __restrict__ va,
                                               const float* __restrict__ vb,
                                               const float* __restrict__ w,
                                               const float* __restrict__ L,
                                               const float* __restrict__ R,
                                               float* __restrict__ ws,
                                               int nvec){
  int bid = blockIdx.x;
  int tid = threadIdx.x;
  int nmain = nvec << 8;            // nvec*256 main blocks
  if (bid >= nmain){
    // ---- init role (32 extra blocks, only on the x+h launch) ----
    int ib = bid - nmain;
    for(int i = ib*256+tid; i < 8*HDIM; i += 32*256)
      ws[OFF_CACHE + 16*HDIM + i] = 0.f;          // zero candidate (sid 2)
    if (ib == 0){
      double s = 0.0;
      for(int d=tid; d<HDIM; d+=256) s += (double)w[d];
      s = wredsumd(s);
      __shared__ double red[4];
      int wv = tid>>6, ln = tid&63;
      if(!ln) red[wv]=s;
      __syncthreads();
      if(tid==0){
        *(double*)(ws + OFF_SUMW_D) = red[0]+red[1]+red[2]+red[3];
        int* st = (int*)(ws + OFF_STATE);
        for(int q=0;q<=8;q++) st[q]=0;
        build_plan(0, 0, st+1, (int*)(ws + OFF_PLAN0));
      }
    }
    return;
  }
  int vec   = bid >> 8;
  int b     = bid & 255;
  int combo = b >> 5;               // 0..7 : m(2) x k(4)
  int hc    = b & 31;               // 32 h-chunks of 64 rows
  const float* v = vec ? vb : va;
  __shared__ float vs[64];
  if (tid < 64) vs[tid] = v[hc*64 + tid];
  __syncthreads();
  int m = combo>>2, k = combo&3;
  const float* M = (m==0?L:R) + (size_t)k*HDIM*HDIM + (size_t)hc*64*HDIM + tid*4;
  float ax0=0.f, ay0=0.f, az0=0.f, aw0=0.f;
  float ax1=0.f, ay1=0.f, az1=0.f, aw1=0.f;
#pragma unroll 8
  for(int h=0; h<64; h++){
    const float4 f0 = *reinterpret_cast<const float4*>(M + (size_t)h*HDIM);
    const float4 f1 = *reinterpret_cast<const float4*>(M + (size_t)h*HDIM + 1024);
    float vv = vs[h];
    ax0 = fmaf(vv, f0.x, ax0); ay0 = fmaf(vv, f0.y, ay0);
    az0 = fmaf(vv, f0.z, az0); aw0 = fmaf(vv, f0.w, aw0);
    ax1 = fmaf(vv, f1.x, ax1); ay1 = fmaf(vv, f1.y, ay1);
    az1 = fmaf(vv, f1.z, az1); aw1 = fmaf(vv, f1.w, aw1);
  }
  float* P = ws + OFF_PART + ((size_t)(vec*8+combo)*32 + hc)*HDIM + tid*4;
  float4 o0; o0.x=ax0; o0.y=ay0; o0.z=az0; o0.w=aw0;
  float4 o1; o1.x=ax1; o1.y=ay1; o1.z=az1; o1.w=aw1;
  *reinterpret_cast<float4*>(P) = o0;
  *reinterpret_cast<float4*>(P + 1024) = o1;
}

// GEMV stage 2: fixed-order (hc ascending) reduction of 32 chunk partials
__global__ __launch_bounds__(256) void kreduce(float* __restrict__ ws, int sid0){
  int b = blockIdx.x;            // nvec*64 blocks
  int vec = b>>6, rem = b&63;
  int combo = rem>>3, dc8 = rem&7;
  int d = dc8*256 + threadIdx.x;
  const float* p = ws + OFF_PART + (size_t)(vec*8+combo)*32*HDIM + d;
  float s = 0.f;
#pragma unroll
  for(int hc=0; hc<32; hc++) s += p[(size_t)hc*HDIM];
  int m = combo>>2, k = combo&3;
  int sid = sid0 + vec;
  ws[OFF_CACHE + ((size_t)(sid*2+m)*NK + k)*HDIM + d] = s;
}

// fused: blocks [0,MAXBASES) = per-base stats (float4, one pass);
// blocks [MAXBASES, +16) = G partial accum (float4, element order preserved)
__global__ __launch_bounds__(256) void kbaseaccum(const float* __restrict__ bvec,
                                                  const float* __restrict__ w,
                                                  float* __restrict__ ws, int par){
  const int* plan = (const int*)(ws + (par ? OFF_PLAN1 : OFF_PLAN0));
  int nb = plan[2];
  int tid = threadIdx.x;
  if (blockIdx.x < MAXBASES){
    int t = blockIdx.x;
    if (t >= nb) return;
    int p = t>>3, k=(t>>1)&3, bf=t&1;
    int si = plan[8+2*MAXPAIRS+p], sj = plan[8+3*MAXPAIRS+p];
    const float* CL = ws + OFF_CACHE + ((size_t)(si*2+0)*NK + k)*HDIM;
    const float* CR = ws + OFF_CACHE + ((size_t)(sj*2+1)*NK + k)*HDIM;
    const float* bk = bvec + (size_t)k*HDIM;
    int d0 = tid*8;
    float am=0.f; double dr=0.0, ds=0.0, dt=0.0;
#pragma unroll
    for(int half=0; half<2; half++){
      int d = d0 + half*4;
      const float4 a4 = *reinterpret_cast<const float4*>(CL + d);
      const float4 c4 = *reinterpret_cast<const float4*>(CR + d);
      const float4 b4 = *reinterpret_cast<const float4*>(bk + d);
      const float4 w4 = *reinterpret_cast<const float4*>(w  + d);
      float av[4]={a4.x,a4.y,a4.z,a4.w};
      float cv[4]={c4.x,c4.y,c4.z,c4.w};
      float bv[4]={b4.x,b4.y,b4.z,b4.w};
      float wv4[4]={w4.x,w4.y,w4.z,w4.w};
#pragma unroll
      for(int q=0;q<4;q++){
        float res = (bf==0) ? __fadd_rn(__fmul_rn(av[q],cv[q]), bv[q])
                            : __fadd_rn(__fadd_rn(av[q],cv[q]), bv[q]);
        float wd = wv4[q];
        am = fmaxf(am, fabsf(res));
        float sg = 1.0f/(1.0f+expf(-res));
        float th = tanhf(res);
        dr += (double)res*(double)wd;
        ds += (double)sg *(double)wd;
        dt += (double)th *(double)wd;
      }
    }
    am = wredmax(am); dr = wredsumd(dr); ds = wredsumd(ds); dt = wredsumd(dt);
    __shared__ double redd[4][3];
    __shared__ float  redm[4];
    int wv = tid>>6, ln = tid&63;
    if(!ln){ redm[wv]=am; redd[wv][0]=dr; redd[wv][1]=ds; redd[wv][2]=dt; }
    __syncthreads();
    if(!tid){
      float A=redm[0]; double Dr=redd[0][0], Ds=redd[0][1], Dt=redd[0][2];
      for(int q=1;q<4;q++){ A=fmaxf(A,redm[q]); Dr+=redd[q][0]; Ds+=redd[q][1]; Dt+=redd[q][2]; }
      ws[OFF_AMAX+t]=A;
      ((double*)(ws+OFF_DOTR_D))[t]=Dr;
      ((double*)(ws+OFF_DOTS_D))[t]=Ds;
      ((double*)(ws+OFF_DOTT_D))[t]=Dt;
    }
  } else {
    // G partial accum: 8 disjoint base-slices x 2 d-halves, float4.
    // Per-element accumulation order over t (ascending within slice bc) is
    // identical to the scalar version -> G bit-identical.
    int bid2 = blockIdx.x - MAXBASES;
    int bc = bid2 >> 1;
    int dh = bid2 & 1;
    int d = dh*1024 + tid*4;
    float acc[4] = {0.f,0.f,0.f,0.f};
    for(int t=bc; t<nb; t+=8){
      int p=t>>3, k=(t>>1)&3, bf=t&1;
      int si = plan[8+2*MAXPAIRS+p], sj = plan[8+3*MAXPAIRS+p];
      const float4 a4 = *reinterpret_cast<const float4*>(ws + OFF_CACHE + ((size_t)(si*2+0)*NK+k)*HDIM + d);
      const float4 c4 = *reinterpret_cast<const float4*>(ws + OFF_CACHE + ((size_t)(sj*2+1)*NK+k)*HDIM + d);
      const float4 b4 = *reinterpret_cast<const float4*>(bvec + (size_t)k*HDIM + d);
      float av[4]={a4.x,a4.y,a4.z,a4.w};
      float cv[4]={c4.x,c4.y,c4.z,c4.w};
      float bv[4]={b4.x,b4.y,b4.z,b4.w};
#pragma unroll
      for(int q=0;q<4;q++){
        float res = (bf==0) ? (av[q]*cv[q] + bv[q]) : (av[q] + cv[q] + bv[q]);
        float ex  = __expf(-res);
        float sig = 1.0f/(1.0f+ex);
        float ex2 = ex*ex;
        float th  = (1.0f-ex2)/(1.0f+ex2);
        acc[q] += sig + th;
      }
    }
    float4 o; o.x=acc[0]; o.y=acc[1]; o.z=acc[2]; o.w=acc[3];
    *reinterpret_cast<float4*>(ws + OFF_GT8 + (size_t)bc*HDIM + d) = o;
  }
}

// selection (double-precision scores) + fused G finalize + output dots
__global__ __launch_bounds__(256) void kselfin(const float* __restrict__ w,
                                               float* __restrict__ ws,
                                               float* __restrict__ out, int r){
  __shared__ double s4[MAXBASES][4];
  __shared__ int    sna[MAXBASES];
  __shared__ double tval[256];
  __shared__ int    tidx[256];
  __shared__ double tz[256];
  __shared__ int    tcnt[256];
  __shared__ double sh_smax;
  __shared__ float  sh_psel;
  __shared__ int    sh_c4;
  int par = r & 1;
  int* plan = (int*)(ws + (par ? OFF_PLAN1 : OFF_PLAN0));
  int nc = plan[0];
  int nb = plan[2];
  double sumw = *(const double*)(ws + OFF_SUMW_D);
  const double* DR = (const double*)(ws+OFF_DOTR_D);
  const double* DS = (const double*)(ws+OFF_DOTS_D);
  const double* DT = (const double*)(ws+OFF_DOTT_D);
  int tid = threadIdx.x;
  for(int t=tid; t<nb; t+=256){
    float A  = ws[OFF_AMAX+t];
    double Dr = DR[t], Ds = DS[t], Dt = DT[t];
    sna[t] = (A < 1.0f) ? 4 : 2;
    s4[t][0] = 0.001*Ds;         // sigmoid
    s4[t][1] = 0.001*Dt;         // tanh
    s4[t][2] = sumw - Dr;        // minus (valid only if na==4)
    s4[t][3] = Dr;               // identity
  }
  __syncthreads();
  // argmax with first-occurrence tie-break (flat q order == entry order)
  double best = -1e300; int bidx = 1<<30;
  for(int q=tid; q<nb*4; q+=256){
    int t=q>>2, a=q&3;
    if (a < sna[t]){
      double v = s4[t][a];
      if (v > best || (v==best && q < bidx)){ best=v; bidx=q; }
    }
  }
  tval[tid]=best; tidx[tid]=bidx;
  __syncthreads();
  if (tid==0){
    double bb=tval[0]; int bi=tidx[0];
    for(int u=1;u<256;u++)
      if (tval[u] > bb || (tval[u]==bb && tidx[u] < bi)){ bb=tval[u]; bi=tidx[u]; }
    sh_smax = bb;
    tidx[0] = bi;
  }
  __syncthreads();
  double smax = sh_smax;
  double s1 = s4[0][1];          // flat entry index 1 is always (base0, tanh)
  double z = 0.0; int cnt = 0;
  for(int q=tid; q<nb*4; q+=256){
    int t=q>>2, a=q&3;
    if (a < sna[t]){
      double v = s4[t][a];
      z += exp(v - smax);
      cnt += (v < s1) ? 1 : 0;
    }
  }
  tz[tid]=z; tcnt[tid]=cnt;
  __syncthreads();
  if (tid==0){
    int bi = tidx[0];
    double Z=0.0; int rank=0;
    for(int u=0;u<256;u++){ Z += tz[u]; rank += tcnt[u]; }
    // score of entry nc-2 (softmax prob numerator)
    int need = nc-2, e=0; double s_sel=0.0;
    for(int t=0;t<nb;t++){
      int n = sna[t];
      if (need < e+n){ s_sel = s4[t][need-e]; break; }
      e += n;
    }
    double psel = exp(s_sel - smax) / Z;
    // second_idx = rank of s[1] used as FLAT index into entries (original bug);
    // output3[r] == scores[second_idx], emit directly.
    int e2=0; double ssec=0.0;
    for(int t=0;t<nb;t++){
      int n = sna[t];
      if (rank < e2+n){ ssec = s4[t][rank-e2]; break; }
      e2 += n;
    }
    out[10*HDIM + 9 + r] = (float)ssec;
    int c4=0;
    for(int t=0;t<nb;t++) c4 += (sna[t]==4) ? 1 : 0;
    int mt = bi>>2;
    int mp = mt>>3;
    int ci = plan[8+mp], cj = plan[8+MAXPAIRS+mp];
    sh_psel = (float)psel;
    sh_c4   = c4;
    // comp_src update (replicates reference branch rules exactly)
    int* st = (int*)(ws + OFF_STATE);
    int lc = st[0];
    int* cs = st+1;
    if (ci>2 && cj>2){
      cs[ci-3] = r;
      for(int q2=cj-3; q2<lc-1; q2++) cs[q2]=cs[q2+1];
      lc--;
    } else if (ci<=2 && cj>2){
      cs[cj-3] = r;
    } else {
      cs[lc] = r; lc++;
    }
    st[0]=lc;
    if (r+1 < NIT)
      build_plan(r+1, lc, cs, (int*)(ws + ((par^1) ? OFF_PLAN1 : OFF_PLAN0)));
  }
  __syncthreads();
  // ---- fused finalize: G[r] from 8 fixed-order slices, G@w dot, output writes ----
  float psel = sh_psel;
  float c4f  = (float)sh_c4;
  float dot = 0.f;
#pragma unroll
  for(int q=0;q<8;q++){
    int d = q*256 + tid;
    float s = 0.f;
#pragma unroll
    for(int bc=0; bc<8; bc++) s += ws[OFF_GT8 + (size_t)bc*HDIM + d];
    float g = psel * (0.001f*s + c4f);
    out[HDIM + (size_t)r*HDIM + d] = g;
    if (r == NIT-1) out[d] = g;
    dot = fmaf(g, w[d], dot);
  }
  dot = wredsum(dot);
  __shared__ float redf[4];
  int wv = tid>>6, ln = tid&63;
  if(!ln) redf[wv]=dot;
  __syncthreads();
  if(!tid) out[10*HDIM + r] = redf[0]+redf[1]+redf[2]+redf[3];
}

extern "C" void kernel_launch(void* const* d_in, const int* in_sizes, int n_in,
                              void* d_out, int out_size, void* d_ws, size_t ws_size,
                              hipStream_t stream){
  const float* x = (const float*)d_in[0];
  const float* h = (const float*)d_in[1];
  const float* L = (const float*)d_in[2];
  const float* R = (const float*)d_in[3];
  const float* b = (const float*)d_in[4];
  const float* w = (const float*)d_in[5];
  float* out = (float*)d_out;
  float* ws  = (float*)d_ws;

  kvecmat<<<512+32,256,0,stream>>>(x, h, w, L, R, ws, 2);   // x,h GEMVs + init
  kreduce<<<128,256,0,stream>>>(ws, 0);                     // sids 0,1
  for(int r=0;r<NIT;r++){
    if (r > 0){
      kvecmat<<<256,256,0,stream>>>(out + HDIM + (size_t)(r-1)*HDIM, nullptr, w, L, R, ws, 1);
      kreduce<<<64,256,0,stream>>>(ws, 3+(r-1));
    }
    kbaseaccum<<<NBS,256,0,stream>>>(b, w, ws, r&1);
    kselfin<<<1,256,0,stream>>>(w, ws, out, r);
  }
}